// Round 2
// baseline (280.431 us; speedup 1.0000x reference)
//
#include <hip/hip_runtime.h>

// Depthwise 41-tap separable gaussian blur of flow = noise*2-1.
// [16, 512, 512, 2] fp32, SAME zero padding.
#define NB   16
#define H    512
#define W    512
#define KW   41
#define HALO 20

// Tile: 64 x-outputs, 52 y-outputs per block; one (batch,channel) per blockIdx.z.
#define TX    64
#define TY    52
#define IN_H  (TY + 2*HALO)   // 92 rows of horizontal-pass results
#define MID_WP 68             // row stride (words): 68*4B=272B=17*16B -> 16B-aligned rows,
                              // phase-2 reads are (x mod 32) banks -> 2-way max (free)
#define PV    (TY / 4)        // 13 outputs per thread in vertical pass

// Raw (unnormalized) gaussian taps exp(-d^2/50), d=-20..20. Normalization (1/sum)^2
// folded into INV_S2 at the epilogue.
constexpr float G[KW] = {
  0.0003354626f, 0.0007318024f, 0.0015338104f, 0.0030887172f,
  0.0059760229f, 0.0111089965f, 0.0198410947f, 0.0340474548f,
  0.0561347628f, 0.0889216176f, 0.1353352832f, 0.1978986990f,
  0.2780373005f, 0.3753110988f, 0.4867522560f, 0.6065306597f,
  0.7261490371f, 0.8352702114f, 0.9231163464f, 0.9801986733f,
  1.0f,
  0.9801986733f, 0.9231163464f, 0.8352702114f, 0.7261490371f,
  0.6065306597f, 0.4867522560f, 0.3753110988f, 0.2780373005f,
  0.1978986990f, 0.1353352832f, 0.0889216176f, 0.0561347628f,
  0.0340474548f, 0.0198410947f, 0.0111089965f, 0.0059760229f,
  0.0030887172f, 0.0015338104f, 0.0007318024f, 0.0003354626f
};

constexpr float gsum() { float s = 0.f; for (int i = 0; i < KW; ++i) s += G[i]; return s; }
constexpr float INV_S2 = 1.0f / (gsum() * gsum());

__global__ __launch_bounds__(256, 6)
void randflow_blur_kernel(const float* __restrict__ noise, float* __restrict__ out) {
    // Only the horizontal-pass intermediate lives in LDS: 92*68*4 = 25024 B
    // -> 6 blocks/CU (150 KB of 160 KB), 24 waves/CU = 75% occupancy.
    __shared__ float s_mid[IN_H][MID_WP];

    const int tid = threadIdx.x;
    const int bx  = blockIdx.x;
    const int tx0 = bx * TX;           // 8 tiles
    const int ty0 = blockIdx.y * TY;   // 10 tiles (covers 520, last rows guarded)
    const int bz  = blockIdx.z;        // b*2 + c
    const int b   = bz >> 1;
    const int c   = bz & 1;

    const float* __restrict__ src = noise + (size_t)b * (H * W * 2) + c;
    const bool xedge = (bx == 0) | (bx == (W / TX - 1));

    // ---- phase 1: horizontal 41-tap conv, global -> s_mid.
    // Work item = (row r of extended tile, 8-output group). 92*8 = 736 items.
    // Sliding window: 48 global loads per 8 outputs (6 loads/output), L1 absorbs
    // the 40/48 overlap between adjacent groups.
    for (int g0 = tid; g0 < IN_H * (TX / 8); g0 += 256) {
        const int r   = g0 >> 3;
        const int ox0 = (g0 & 7) << 3;
        const int yin = ty0 + r - HALO;

        float acc[8] = {0.f,0.f,0.f,0.f,0.f,0.f,0.f,0.f};

        if ((unsigned)yin < (unsigned)H) {   // loop-invariant row guard
            const int xbase = tx0 + ox0 - HALO;
            const float* __restrict__ rp = src + ((size_t)yin * W + xbase) * 2;
            if (!xedge) {
                #pragma unroll
                for (int j = 0; j < 8 + KW - 1; ++j) {
                    float v = __builtin_fmaf(rp[2 * j], 2.0f, -1.0f);
                    #pragma unroll
                    for (int p = 0; p < 8; ++p) {
                        int t = j - p;                  // compile-time after unroll
                        if (t >= 0 && t < KW)
                            acc[p] = __builtin_fmaf(G[t], v, acc[p]);
                    }
                }
            } else {
                #pragma unroll
                for (int j = 0; j < 8 + KW - 1; ++j) {
                    const int xin = xbase + j;
                    float v = 0.0f;
                    if ((unsigned)xin < (unsigned)W)    // guarded load (no OOB deref)
                        v = __builtin_fmaf(rp[2 * j], 2.0f, -1.0f);
                    #pragma unroll
                    for (int p = 0; p < 8; ++p) {
                        int t = j - p;
                        if (t >= 0 && t < KW)
                            acc[p] = __builtin_fmaf(G[t], v, acc[p]);
                    }
                }
            }
        }
        // 16B-aligned (row stride 272 B, ox0*4 multiple of 32 B): 2x ds_write_b128
        *(float4*)&s_mid[r][ox0]     = make_float4(acc[0], acc[1], acc[2], acc[3]);
        *(float4*)&s_mid[r][ox0 + 4] = make_float4(acc[4], acc[5], acc[6], acc[7]);
    }
    __syncthreads();

    // ---- phase 2: vertical 41-tap conv, s_mid -> out. One x-column per thread,
    // PV=13 consecutive y outputs, 53 reads per 13 outputs (4.1/output).
    // Lane x consecutive -> bank = x mod 32 -> 2-way max (free).
    {
        const int x   = tid & 63;
        const int grp = tid >> 6;       // 0..3
        const int py0 = grp * PV;       // 0,13,26,39
        float acc[PV];
        #pragma unroll
        for (int p = 0; p < PV; ++p) acc[p] = 0.f;
        #pragma unroll
        for (int j = 0; j < PV + KW - 1; ++j) {     // 53 iters, max row 39+52=91=IN_H-1
            float v = s_mid[py0 + j][x];
            #pragma unroll
            for (int p = 0; p < PV; ++p) {
                int t = j - p;
                if (t >= 0 && t < KW)
                    acc[p] = __builtin_fmaf(G[t], v, acc[p]);
            }
        }
        const int xo = tx0 + x;
        #pragma unroll
        for (int p = 0; p < PV; ++p) {
            int yo = ty0 + py0 + p;
            if (yo < H) {
                out[(((size_t)b * H + yo) * W + xo) * 2 + c] = acc[p] * INV_S2;
            }
        }
    }
}

extern "C" void kernel_launch(void* const* d_in, const int* in_sizes, int n_in,
                              void* d_out, int out_size, void* d_ws, size_t ws_size,
                              hipStream_t stream) {
    // d_in[0] = inputs [16,512,512,1]  -- UNUSED by the reference
    // d_in[1] = rand_noise [16,512,512,2] fp32
    const float* noise = (const float*)d_in[1];
    float* out = (float*)d_out;

    dim3 grid(W / TX, (H + TY - 1) / TY, NB * 2);   // 8 x 10 x 32 = 2560 blocks
    dim3 block(256);
    randflow_blur_kernel<<<grid, block, 0, stream>>>(noise, out);
}

// Round 3
// 134.990 us; speedup vs baseline: 2.0774x; 2.0774x over previous
//
#include <hip/hip_runtime.h>

// Depthwise 41-tap separable gaussian blur of flow = noise*2-1.
// [16, 512, 512, 2] fp32, SAME zero padding.
//
// R3 structure: vertical pass FIRST (dense float2 global loads, lanes along x,
// both channels at once), intermediate in LDS transposed [x][y], horizontal
// pass slides along x in LDS, dense float2 stores.
#define NB   16
#define H    512
#define W    512
#define KW   41
#define HALO 20

#define TX   88     // output columns per block (6 x-blocks cover 512+16 waste)
#define TY   32     // output rows per block (16 y-blocks, exact)
#define IN_W (TX + 2*HALO)   // 128 intermediate columns
#define PVV  16     // vertical outputs per thread: 128 cols x 2 ygroups = 256 items
#define PX   11     // horizontal outputs per thread: 8 xgroups x 32 rows = 256 items
#define COL_F2 (TY + 1)      // 33 float2 per LDS column -> stride 66 words

// Raw gaussian taps exp(-d^2/50), d=-20..20; (1/sum)^2 folded into INV_S2.
constexpr float G[KW] = {
  0.0003354626f, 0.0007318024f, 0.0015338104f, 0.0030887172f,
  0.0059760229f, 0.0111089965f, 0.0198410947f, 0.0340474548f,
  0.0561347628f, 0.0889216176f, 0.1353352832f, 0.1978986990f,
  0.2780373005f, 0.3753110988f, 0.4867522560f, 0.6065306597f,
  0.7261490371f, 0.8352702114f, 0.9231163464f, 0.9801986733f,
  1.0f,
  0.9801986733f, 0.9231163464f, 0.8352702114f, 0.7261490371f,
  0.6065306597f, 0.4867522560f, 0.3753110988f, 0.2780373005f,
  0.1978986990f, 0.1353352832f, 0.0889216176f, 0.0561347628f,
  0.0340474548f, 0.0198410947f, 0.0111089965f, 0.0059760229f,
  0.0030887172f, 0.0015338104f, 0.0007318024f, 0.0003354626f
};

constexpr float gsum() { float s = 0.f; for (int i = 0; i < KW; ++i) s += G[i]; return s; }
constexpr float INV_S2 = 1.0f / (gsum() * gsum());

__global__ __launch_bounds__(256, 4)
void randflow_blur_kernel(const float* __restrict__ noise, float* __restrict__ out) {
    // Transposed intermediate: column sx holds TY y-values (float2 = both channels).
    // 128 * 33 * 8 = 33792 B -> 4 blocks/CU (135 KB), 16 waves/CU.
    __shared__ float2 s_mid[IN_W * COL_F2];

    const int tid = threadIdx.x;
    const int bx  = blockIdx.x;
    const int by  = blockIdx.y;
    const int b   = blockIdx.z;
    const int tx0 = bx * TX;
    const int ty0 = by * TY;
    const float* __restrict__ src = noise + (size_t)b * (H * W * 2);

    // ---- phase 1: vertical 41-tap conv, global -> s_mid (transposed).
    // Thread = (column sx, ygroup). Loads: lanes along sx -> 64 consecutive
    // float2 = 512 B dense per wave-load. 56 loads per 16 outputs.
    {
        const int sx  = tid & 127;          // 0..127
        const int yg  = tid >> 7;           // 0..1
        const int gx  = tx0 + sx - HALO;
        const int cgx = min(max(gx, 0), W - 1);
        const bool vx = (gx == cgx);
        // fold x-validity into the flow transform: v = vx ? (2u-1) : 0
        const float sa = vx ? 2.0f : 0.0f;
        const float sb = vx ? -1.0f : 0.0f;
        const int  ysb = ty0 + yg * PVV - HALO;
        const float* __restrict__ colp = src + 2 * cgx;

        float2 acc[PVV];
        #pragma unroll
        for (int p = 0; p < PVV; ++p) acc[p] = make_float2(0.f, 0.f);

        #pragma unroll
        for (int j = 0; j < PVV + KW - 1; ++j) {          // 56 rows
            const int ys = ysb + j;
            const int cy = min(max(ys, 0), H - 1);        // clamped -> load always legal
            const float a  = (ys == cy) ? sa : 0.0f;      // row-validity select
            const float bb = (ys == cy) ? sb : 0.0f;
            const float2 u = *(const float2*)(colp + (size_t)cy * (W * 2));
            float2 v;
            v.x = __builtin_fmaf(u.x, a, bb);
            v.y = __builtin_fmaf(u.y, a, bb);
            #pragma unroll
            for (int p = 0; p < PVV; ++p) {
                const int t = j - p;                      // compile-time after unroll
                if (t >= 0 && t < KW) {
                    acc[p].x = __builtin_fmaf(G[t], v.x, acc[p].x);
                    acc[p].y = __builtin_fmaf(G[t], v.y, acc[p].y);
                }
            }
        }
        #pragma unroll
        for (int p = 0; p < PVV; ++p)
            s_mid[sx * COL_F2 + yg * PVV + p] = acc[p];
    }
    __syncthreads();

    // ---- phase 2: horizontal 41-tap conv, s_mid -> out.
    // Thread = (xgroup of 11 outputs, row y). For fixed tap, lanes read
    // 32 consecutive float2 (dense burst) with 2-way broadcast -> conflict-free.
    {
        const int y  = tid & 31;
        const int xg = tid >> 5;            // 0..7
        const int x0 = xg * PX;

        float2 acc[PX];
        #pragma unroll
        for (int p = 0; p < PX; ++p) acc[p] = make_float2(0.f, 0.f);

        #pragma unroll
        for (int j = 0; j < PX + KW - 1; ++j) {           // 51 taps window
            const float2 v = s_mid[(x0 + j) * COL_F2 + y];
            #pragma unroll
            for (int p = 0; p < PX; ++p) {
                const int t = j - p;
                if (t >= 0 && t < KW) {
                    acc[p].x = __builtin_fmaf(G[t], v.x, acc[p].x);
                    acc[p].y = __builtin_fmaf(G[t], v.y, acc[p].y);
                }
            }
        }

        const int yo = ty0 + y;
        float* __restrict__ orow = out + (((size_t)b * H + yo) * W) * 2;
        #pragma unroll
        for (int p = 0; p < PX; ++p) {
            const int xo = tx0 + x0 + p;
            if (xo < W) {                                  // only bx=5 clips
                float2 r;
                r.x = acc[p].x * INV_S2;
                r.y = acc[p].y * INV_S2;
                *(float2*)(orow + 2 * xo) = r;             // dense 8B store, both channels
            }
        }
    }
}

extern "C" void kernel_launch(void* const* d_in, const int* in_sizes, int n_in,
                              void* d_out, int out_size, void* d_ws, size_t ws_size,
                              hipStream_t stream) {
    // d_in[0] = inputs [16,512,512,1]  -- UNUSED by the reference
    // d_in[1] = rand_noise [16,512,512,2] fp32
    const float* noise = (const float*)d_in[1];
    float* out = (float*)d_out;

    dim3 grid((W + TX - 1) / TX, H / TY, NB);   // 6 x 16 x 16 = 1536 blocks
    dim3 block(256);
    randflow_blur_kernel<<<grid, block, 0, stream>>>(noise, out);
}

// Round 4
// 124.164 us; speedup vs baseline: 2.2585x; 1.0872x over previous
//
#include <hip/hip_runtime.h>

// Depthwise 41-tap separable gaussian blur of flow = noise*2-1.
// [16, 512, 512, 2] fp32, SAME zero padding.
//
// R4: phase 1 vertical conv (dense float2 global loads, lanes along x, both
// channels), s_mid row-major in LDS; phase 2 horizontal conv sliding along x
// in LDS; phase 3 LDS transpose round-trip so global stores are lane-dense.
#define NB   16
#define H    512
#define W    512
#define KW   41
#define HALO 20

#define TX   88              // output cols per block (6 x-blocks)
#define TY   32              // output rows per block (16 y-blocks)
#define IN_W 128             // TX + 2*HALO intermediate columns
#define PVV  16              // vertical outputs/thread (128 cols x 2 ygroups = 256)
#define PX   11              // horizontal outputs/thread (8 xgroups x 32 rows = 256)
#define MSTR 129             // s_mid row stride in float2 (pad: banks spread 2y)
#define OSTR 89              // s_out row stride in float2
#define SMEM_F2 (TY * MSTR)  // 4128 float2 = 33024 B (s_out 32*89=2848 aliases inside)

// Raw gaussian taps exp(-d^2/50), d=-20..20; (1/sum)^2 folded into INV_S2.
constexpr float G[KW] = {
  0.0003354626f, 0.0007318024f, 0.0015338104f, 0.0030887172f,
  0.0059760229f, 0.0111089965f, 0.0198410947f, 0.0340474548f,
  0.0561347628f, 0.0889216176f, 0.1353352832f, 0.1978986990f,
  0.2780373005f, 0.3753110988f, 0.4867522560f, 0.6065306597f,
  0.7261490371f, 0.8352702114f, 0.9231163464f, 0.9801986733f,
  1.0f,
  0.9801986733f, 0.9231163464f, 0.8352702114f, 0.7261490371f,
  0.6065306597f, 0.4867522560f, 0.3753110988f, 0.2780373005f,
  0.1978986990f, 0.1353352832f, 0.0889216176f, 0.0561347628f,
  0.0340474548f, 0.0198410947f, 0.0111089965f, 0.0059760229f,
  0.0030887172f, 0.0015338104f, 0.0007318024f, 0.0003354626f
};

constexpr float gsum() { float s = 0.f; for (int i = 0; i < KW; ++i) s += G[i]; return s; }
constexpr float INV_S2 = 1.0f / (gsum() * gsum());

__global__ __launch_bounds__(256, 4)
void randflow_blur_kernel(const float* __restrict__ noise, float* __restrict__ out) {
    __shared__ float2 smem[SMEM_F2];   // 33024 B -> 4 blocks/CU, 16 waves/CU

    const int tid = threadIdx.x;
    const int bx  = blockIdx.x;
    const int tx0 = bx * TX;
    const int ty0 = blockIdx.y * TY;
    const int b   = blockIdx.z;
    const float* __restrict__ src = noise + (size_t)b * (H * W * 2);

    // ---- phase 1: vertical 41-tap conv, global -> s_mid[y][x] (row-major).
    // Thread = (col sx, ygroup). Wave loads 64 consecutive float2 = 512 B dense.
    // 56 loads per 16 outputs. Zero-pad folded into per-row/col selects on
    // clamped (always-legal) addresses -> no exec-mask divergence on loads.
    {
        const int sx  = tid & 127;
        const int yg  = tid >> 7;
        const int gx  = tx0 + sx - HALO;
        const int cgx = min(max(gx, 0), W - 1);
        const float sa = (gx == cgx) ? 2.0f : 0.0f;   // x-validity folded in
        const float sb = (gx == cgx) ? -1.0f : 0.0f;
        const int  ysb = ty0 + yg * PVV - HALO;
        const float* __restrict__ colp = src + 2 * cgx;

        float2 acc[PVV];
        #pragma unroll
        for (int p = 0; p < PVV; ++p) acc[p] = make_float2(0.f, 0.f);

        #pragma unroll
        for (int j = 0; j < PVV + KW - 1; ++j) {      // 56 rows
            const int ys = ysb + j;
            const int cy = min(max(ys, 0), H - 1);
            const float a  = (ys == cy) ? sa : 0.0f;  // y-validity select
            const float bb = (ys == cy) ? sb : 0.0f;
            const float2 u = *(const float2*)(colp + (size_t)cy * (W * 2));
            float2 v;
            v.x = __builtin_fmaf(u.x, a, bb);
            v.y = __builtin_fmaf(u.y, a, bb);
            #pragma unroll
            for (int p = 0; p < PVV; ++p) {
                const int t = j - p;                  // compile-time after unroll
                if (t >= 0 && t < KW) {
                    acc[p].x = __builtin_fmaf(G[t], v.x, acc[p].x);
                    acc[p].y = __builtin_fmaf(G[t], v.y, acc[p].y);
                }
            }
        }
        #pragma unroll
        for (int p = 0; p < PVV; ++p)                 // lanes along sx: dense writes
            smem[(yg * PVV + p) * MSTR + sx] = acc[p];
    }
    __syncthreads();

    // ---- phase 2: horizontal 41-tap conv in LDS, results to registers.
    // Thread = (xgroup, row y); 51 reads per 11 outputs.
    const int y  = tid & 31;
    const int xg = tid >> 5;
    const int x0 = xg * PX;
    float2 facc[PX];
    {
        #pragma unroll
        for (int p = 0; p < PX; ++p) facc[p] = make_float2(0.f, 0.f);
        #pragma unroll
        for (int j = 0; j < PX + KW - 1; ++j) {       // 51
            const float2 v = smem[y * MSTR + x0 + j];
            #pragma unroll
            for (int p = 0; p < PX; ++p) {
                const int t = j - p;
                if (t >= 0 && t < KW) {
                    facc[p].x = __builtin_fmaf(G[t], v.x, facc[p].x);
                    facc[p].y = __builtin_fmaf(G[t], v.y, facc[p].y);
                }
            }
        }
    }
    __syncthreads();   // all s_mid reads done; safe to overwrite aliased region

    // write results back to LDS (s_out aliases smem), store-order friendly
    #pragma unroll
    for (int p = 0; p < PX; ++p) {
        float2 r;
        r.x = facc[p].x * INV_S2;
        r.y = facc[p].y * INV_S2;
        smem[y * OSTR + x0 + p] = r;
    }
    __syncthreads();

    // ---- phase 3: lane-dense global stores. 2816 float2, 11 per thread;
    // consecutive lanes -> consecutive x -> full-line 512 B bursts.
    #pragma unroll
    for (int p = 0; p < PX; ++p) {
        const int flat = p * 256 + tid;
        const int ry = flat / TX;          // const divide -> magic mul
        const int rx = flat - ry * TX;
        const int xo = tx0 + rx;
        if (xo < W) {                      // only bx=5 clips
            const int yo = ty0 + ry;
            *(float2*)(out + (((size_t)b * H + yo) * W + xo) * 2) = smem[ry * OSTR + rx];
        }
    }
}

extern "C" void kernel_launch(void* const* d_in, const int* in_sizes, int n_in,
                              void* d_out, int out_size, void* d_ws, size_t ws_size,
                              hipStream_t stream) {
    // d_in[0] = inputs [16,512,512,1]  -- UNUSED by the reference
    // d_in[1] = rand_noise [16,512,512,2] fp32
    const float* noise = (const float*)d_in[1];
    float* out = (float*)d_out;

    dim3 grid((W + TX - 1) / TX, H / TY, NB);   // 6 x 16 x 16 = 1536 blocks
    dim3 block(256);
    randflow_blur_kernel<<<grid, block, 0, stream>>>(noise, out);
}